// Round 3
// baseline (246.682 us; speedup 1.0000x reference)
//
#include <hip/hip_runtime.h>
#include <stdint.h>

#define BATCH 8
#define SEQ 2048
#define DIM 1024
#define MTOT (BATCH * SEQ)   // 16384

typedef __attribute__((ext_vector_type(8))) short short8;
typedef __attribute__((ext_vector_type(8))) unsigned short ushort8;
typedef __attribute__((ext_vector_type(4))) float floatx4;

// ---------- helpers ----------

__device__ __forceinline__ unsigned short f2bf(float f) {
  union { float f; unsigned u; } c; c.f = f;
  unsigned u = c.u;
  return (unsigned short)((u + 0x7FFFu + ((u >> 16) & 1u)) >> 16);
}
__device__ __forceinline__ float bf2f(unsigned short h) {
  union { unsigned u; float f; } c; c.u = ((unsigned)h) << 16;
  return c.f;
}

__device__ __forceinline__ void gll16(const void* g, void* l) {
  __builtin_amdgcn_global_load_lds(
      (__attribute__((address_space(1))) void*)(uintptr_t)g,
      (__attribute__((address_space(3))) void*)(uintptr_t)l,
      16, 0, 0);
}

// ---------- cast fp32->bf16 (x, B, W) + apow table a[n]^(t+1) -------------

#define X4 (MTOT * DIM / 4)   // 4194304
#define M4 (DIM * DIM / 4)    // 262144
#define TAB_N (128 * DIM)     // 131072 entries, 512 KB

__global__ __launch_bounds__(256) void cast3_kernel(
    const float* __restrict__ x, const float* __restrict__ B,
    const float* __restrict__ W, unsigned short* __restrict__ xb,
    unsigned short* __restrict__ Bb, unsigned short* __restrict__ Wb,
    const float* __restrict__ Adiag, float* __restrict__ tab) {
  int i = blockIdx.x * 256 + threadIdx.x;
  if (i >= X4 + 2 * M4) {
    // apow table: tab[t][n] = a[n]^(t+1), t in 0..127
    int idx = i - (X4 + 2 * M4);
    int t = idx >> 10, n = idx & (DIM - 1);
    float a = Adiag[n];
    tab[idx] = __builtin_amdgcn_exp2f(__builtin_amdgcn_logf(a) *
                                      (float)(t + 1));
    return;
  }
  const float4* s4;
  uint2* d2;
  int li;
  if (i < X4) {
    s4 = (const float4*)x; d2 = (uint2*)xb; li = i;
  } else if (i < X4 + M4) {
    s4 = (const float4*)B; d2 = (uint2*)Bb; li = i - X4;
  } else {
    s4 = (const float4*)W; d2 = (uint2*)Wb; li = i - X4 - M4;
  }
  float4 v = s4[li];
  uint2 o;
  o.x = (unsigned)f2bf(v.x) | ((unsigned)f2bf(v.y) << 16);
  o.y = (unsigned)f2bf(v.z) | ((unsigned)f2bf(v.w) << 16);
  d2[li] = o;
}

// ---------- GEMM1 fused with chunk-local scan + aggregate publish ----------
// Round-0 verified form: bf16 A and B both staged via global_load_lds.

__global__ __launch_bounds__(256) void gemm1_fused(
    const unsigned short* __restrict__ A,   // xb bf16 [M x 1024]
    const unsigned short* __restrict__ B,   // Bb bf16 [1024 x 1024]
    unsigned short* __restrict__ u,         // h_local out bf16
    const float* __restrict__ Adiag,
    float* __restrict__ aggbuf) {           // [128][1024] fp32
  __shared__ unsigned short smem[16384];    // sA|sB, reused as sC (32 KB)
  __shared__ float segsum[2][128];
  unsigned short* sA = smem;
  unsigned short* sB = smem + 8192;

  const int tid = threadIdx.x;
  const int wave = tid >> 6, lane = tid & 63;

  // XCD-aware tile remap (measured FETCH=ideal)
  const int id = blockIdx.x;
  const int xcd = id & 7, j = id >> 3;
  const int mt = xcd * 16 + (j >> 3);
  const int nt = j & 7;
  const size_t m0 = (size_t)mt * 128;
  const int n0 = nt * 128;

  floatx4 acc[4][4] = {};

  const int srow = wave * 8 + (lane >> 3);
  const int scol = (((lane & 7) ^ ((lane >> 3) & 7)) * 8);  // XOR swizzle
  const unsigned short* gA = A + (m0 + srow) * 1024 + scol;
  const unsigned short* gB = B + ((size_t)n0 + srow) * 1024 + scol;
  unsigned short* lA = sA + wave * 8 * 64;
  unsigned short* lB = sB + wave * 8 * 64;

  const int fr = lane & 15;
  const int frs = fr & 7;
  const int kb = lane >> 4;
  const int wm = (wave & 1) * 64, wn = (wave >> 1) * 64;

  for (int kt = 0; kt < 1024; kt += 64) {
#pragma unroll
    for (int r = 0; r < 4; ++r) {
      gll16(gA + (size_t)r * 32 * 1024 + kt, lA + r * 32 * 64);
      gll16(gB + (size_t)r * 32 * 1024 + kt, lB + r * 32 * 64);
    }
    asm volatile("s_waitcnt vmcnt(0)" ::: "memory");
    __syncthreads();
#pragma unroll
    for (int kk = 0; kk < 64; kk += 32) {
      short8 af[4], bfv[4];
#pragma unroll
      for (int i = 0; i < 4; ++i)
        af[i] = *(const short8*)(sA + (wm + i * 16 + fr) * 64 +
                                 ((((kk >> 3) + kb) ^ frs) * 8));
#pragma unroll
      for (int jj = 0; jj < 4; ++jj)
        bfv[jj] = *(const short8*)(sB + (wn + jj * 16 + fr) * 64 +
                                   ((((kk >> 3) + kb) ^ frs) * 8));
#pragma unroll
      for (int i = 0; i < 4; ++i)
#pragma unroll
        for (int jj = 0; jj < 4; ++jj)
          acc[i][jj] = __builtin_amdgcn_mfma_f32_16x16x32_bf16(
              af[i], bfv[jj], acc[i][jj], 0, 0, 0);
    }
    __syncthreads();
  }

  // stage u tile in LDS (C/D map: col=lane&15, row=(lane>>4)*4+reg)
  const int col = lane & 15;
  const int row4 = (lane >> 4) * 4;
  unsigned short* sC = smem;  // 128x128 bf16
#pragma unroll
  for (int i = 0; i < 4; ++i)
#pragma unroll
    for (int jj = 0; jj < 4; ++jj)
#pragma unroll
      for (int r = 0; r < 4; ++r)
        sC[(wm + i * 16 + row4 + r) * 128 + wn + jj * 16 + col] =
            f2bf(acc[i][jj][r]);
  __syncthreads();

  // chunk-local scan: 2 segments x 64 t per column (tid -> col, seg)
  const int colv = tid & 127;
  const int seg = tid >> 7;
  const float a = Adiag[n0 + colv];
  {
    float s = 0.f;
    const int t0 = seg * 64;
#pragma unroll 8
    for (int t = 0; t < 64; ++t) {
      int idx = (t0 + t) * 128 + colv;
      s = fmaf(a, s, bf2f(sC[idx]));
      sC[idx] = f2bf(s);
    }
    segsum[seg][colv] = s;
  }
  __syncthreads();

  // correct rows 64..127 with seg-0 end state; publish aggregate
  {
    float a2 = a * a, a4 = a2 * a2, a8 = a4 * a4, a16 = a8 * a8;
    float a32 = a16 * a16, a64 = a32 * a32;
    const float s0 = segsum[0][colv];
    const int t0 = 64 + seg * 32;
    float apow = seg ? a32 * a : a;  // a^(t0-64+1)
#pragma unroll 8
    for (int t = 0; t < 32; ++t) {
      int idx = (t0 + t) * 128 + colv;
      sC[idx] = f2bf(fmaf(apow, s0, bf2f(sC[idx])));
      apow *= a;
    }
    if (seg)
      aggbuf[(size_t)mt * 1024 + n0 + colv] =
          fmaf(a64, s0, segsum[1][colv]);
  }
  __syncthreads();

  // coalesced 16B h_local stores
#pragma unroll
  for (int s = 0; s < 8; ++s) {
    int row = wave * 32 + s * 4 + (lane >> 4);
    int c8 = (lane & 15) * 8;
    *(ushort8*)(u + (m0 + row) * (size_t)1024 + n0 + c8) =
        *(const ushort8*)(sC + row * 128 + c8);
  }
}

// ---------- combine: exclusive scan of 16 chunk aggregates per (b, n) ------

__global__ __launch_bounds__(256) void combine_kernel(
    const float* __restrict__ agg, float* __restrict__ carry,
    const float* __restrict__ Adiag) {
  const int id = blockIdx.x * 256 + threadIdx.x;  // 0..8191
  const int b = id >> 10, n = id & (DIM - 1);
  float a = Adiag[n];
  float aL = a;
#pragma unroll
  for (int i = 0; i < 7; ++i) aL *= aL;  // a^128
  float s = 0.f;
#pragma unroll
  for (int c = 0; c < 16; ++c) {
    size_t idx = (size_t)(b * 16 + c) * 1024 + n;
    float local = agg[idx];
    carry[idx] = s;           // carry-in for chunk c
    s = fmaf(aL, s, local);
  }
}

// ---------- GEMM2 fused: y = (h_local + tab[t]*carry) . W^T + bias --------
// apply folded into A-staging; a^(t+1) comes from the precomputed table
// (L2-resident, 512 KB shared by all blocks) — zero transcendentals in the
// K-loop. LDS layout and read path identical to the verified kernel.

__global__ __launch_bounds__(256) void gemm2_fused(
    const unsigned short* __restrict__ A,   // h_local bf16
    const unsigned short* __restrict__ Bw,  // Wb bf16
    float* __restrict__ C, const float* __restrict__ bias,
    const float* __restrict__ tab,          // [128][1024] a^(t+1)
    const float* __restrict__ carry) {
  __shared__ unsigned short smem[16384];
  unsigned short* sA = smem;
  unsigned short* sB = smem + 8192;

  const int tid = threadIdx.x;
  const int wave = tid >> 6, lane = tid & 63;

  const int id = blockIdx.x;
  const int xcd = id & 7, j = id >> 3;
  const int mt = xcd * 16 + (j >> 3);
  const int nt = j & 7;
  const size_t m0 = (size_t)mt * 128;
  const int n0 = nt * 128;

  floatx4 acc[4][4] = {};

  const int srow = wave * 8 + (lane >> 3);           // local t in 0..31 (+r*32)
  const int scol = (((lane & 7) ^ ((lane >> 3) & 7)) * 8);
  const unsigned short* gA = A + (m0 + srow) * 1024 + scol;
  const unsigned short* gB = Bw + ((size_t)n0 + srow) * 1024 + scol;
  unsigned short* lA = sA + wave * 8 * 64 + lane * 8;
  unsigned short* lB = sB + wave * 8 * 64;
  const float* cbase = carry + (size_t)mt * 1024;
  const float* tbase = tab + (size_t)srow * 1024 + scol;

  const int fr = lane & 15;
  const int frs = fr & 7;
  const int kb = lane >> 4;
  const int wm = (wave & 1) * 64, wn = (wave >> 1) * 64;

  for (int kt = 0; kt < 1024; kt += 64) {
    // A: h_local bf16 reg loads + carry (L2-hot)
    ushort8 hv[4];
#pragma unroll
    for (int r = 0; r < 4; ++r)
      hv[r] = *(const ushort8*)(gA + (size_t)r * 32 * 1024 + kt);
    float4 cf0 = *(const float4*)(cbase + kt + scol);
    float4 cf1 = *(const float4*)(cbase + kt + scol + 4);
    // B: direct-to-LDS
#pragma unroll
    for (int r = 0; r < 4; ++r)
      gll16(gB + (size_t)r * 32 * 1024 + kt, lB + r * 32 * 64);

    float cf[8] = {cf0.x, cf0.y, cf0.z, cf0.w, cf1.x, cf1.y, cf1.z, cf1.w};
#pragma unroll
    for (int r = 0; r < 4; ++r) {
      // apow for t = srow + r*32, columns kt+scol..+7 (table, L2-resident)
      float4 t0 = *(const float4*)(tbase + r * 32 * 1024 + kt);
      float4 t1 = *(const float4*)(tbase + r * 32 * 1024 + kt + 4);
      float tq[8] = {t0.x, t0.y, t0.z, t0.w, t1.x, t1.y, t1.z, t1.w};
      ushort8 o;
#pragma unroll
      for (int q = 0; q < 8; ++q)
        o[q] = f2bf(fmaf(tq[q], cf[q], bf2f(hv[r][q])));
      *(ushort8*)(lA + r * 32 * 64) = o;
    }
    asm volatile("s_waitcnt vmcnt(0)" ::: "memory");
    __syncthreads();
#pragma unroll
    for (int kk = 0; kk < 64; kk += 32) {
      short8 af[4], bfv[4];
#pragma unroll
      for (int i = 0; i < 4; ++i)
        af[i] = *(const short8*)(sA + (wm + i * 16 + fr) * 64 +
                                 ((((kk >> 3) + kb) ^ frs) * 8));
#pragma unroll
      for (int jj = 0; jj < 4; ++jj)
        bfv[jj] = *(const short8*)(sB + (wn + jj * 16 + fr) * 64 +
                                   ((((kk >> 3) + kb) ^ frs) * 8));
#pragma unroll
      for (int i = 0; i < 4; ++i)
#pragma unroll
        for (int jj = 0; jj < 4; ++jj)
          acc[i][jj] = __builtin_amdgcn_mfma_f32_16x16x32_bf16(
              af[i], bfv[jj], acc[i][jj], 0, 0, 0);
    }
    __syncthreads();
  }

  const int col = lane & 15;
  const int row4 = (lane >> 4) * 4;
#pragma unroll
  for (int i = 0; i < 4; ++i)
#pragma unroll
    for (int jj = 0; jj < 4; ++jj)
#pragma unroll
      for (int r = 0; r < 4; ++r) {
        size_t m = m0 + wm + i * 16 + row4 + r;
        int n = n0 + wn + jj * 16 + col;
        C[m * 1024 + n] = acc[i][jj][r] + bias[n];
      }
}

// ---------- launcher ----------

extern "C" void kernel_launch(void* const* d_in, const int* in_sizes, int n_in,
                              void* d_out, int out_size, void* d_ws,
                              size_t ws_size, hipStream_t stream) {
  const float* x    = (const float*)d_in[0];
  const float* A    = (const float*)d_in[1];
  const float* B    = (const float*)d_in[2];
  const float* W    = (const float*)d_in[3];
  const float* bias = (const float*)d_in[4];

  char* ws = (char*)d_ws;
  unsigned short* xb   = (unsigned short*)ws;              // 32 MB
  unsigned short* ubuf = (unsigned short*)(ws + 33554432); // 32 MB (h_local)
  unsigned short* Bb   = (unsigned short*)(ws + 67108864); //  2 MB
  unsigned short* Wb   = (unsigned short*)(ws + 69206016); //  2 MB
  float* aggbuf        = (float*)(ws + 71303168);          // 512 KB
  float* carry         = (float*)(ws + 71827456);          // 512 KB
  float* tab           = (float*)(ws + 72351744);          // 512 KB apow table

  cast3_kernel<<<(X4 + 2 * M4 + TAB_N) / 256, 256, 0, stream>>>(
      x, B, W, xb, Bb, Wb, A, tab);

  gemm1_fused<<<1024, 256, 0, stream>>>(xb, Bb, ubuf, A, aggbuf);

  combine_kernel<<<32, 256, 0, stream>>>(aggbuf, carry, A);

  gemm2_fused<<<1024, 256, 0, stream>>>(ubuf, Wb, (float*)d_out, bias, tab, carry);
}

// Round 4
// 229.571 us; speedup vs baseline: 1.0745x; 1.0745x over previous
//
#include <hip/hip_runtime.h>
#include <stdint.h>

#define BATCH 8
#define SEQ 2048
#define DIM 1024
#define MTOT (BATCH * SEQ)   // 16384

typedef __attribute__((ext_vector_type(8))) short short8;
typedef __attribute__((ext_vector_type(8))) unsigned short ushort8;
typedef __attribute__((ext_vector_type(4))) float floatx4;

// ---------- helpers ----------

__device__ __forceinline__ unsigned short f2bf(float f) {
  union { float f; unsigned u; } c; c.f = f;
  unsigned u = c.u;
  return (unsigned short)((u + 0x7FFFu + ((u >> 16) & 1u)) >> 16);
}
__device__ __forceinline__ float bf2f(unsigned short h) {
  union { unsigned u; float f; } c; c.u = ((unsigned)h) << 16;
  return c.f;
}

__device__ __forceinline__ void gll16(const void* g, void* l) {
  __builtin_amdgcn_global_load_lds(
      (__attribute__((address_space(1))) void*)(uintptr_t)g,
      (__attribute__((address_space(3))) void*)(uintptr_t)l,
      16, 0, 0);
}

// ---------- cast fp32->bf16 (x, B, W), one float4 -> uint2 per thread ------

#define X4 (MTOT * DIM / 4)   // 4194304
#define M4 (DIM * DIM / 4)    // 262144

__global__ __launch_bounds__(256) void cast3_kernel(
    const float* __restrict__ x, const float* __restrict__ B,
    const float* __restrict__ W, unsigned short* __restrict__ xb,
    unsigned short* __restrict__ Bb, unsigned short* __restrict__ Wb) {
  int i = blockIdx.x * 256 + threadIdx.x;
  const float4* s4;
  uint2* d2;
  int li;
  if (i < X4) {
    s4 = (const float4*)x; d2 = (uint2*)xb; li = i;
  } else if (i < X4 + M4) {
    s4 = (const float4*)B; d2 = (uint2*)Bb; li = i - X4;
  } else {
    s4 = (const float4*)W; d2 = (uint2*)Wb; li = i - X4 - M4;
  }
  float4 v = s4[li];
  uint2 o;
  o.x = (unsigned)f2bf(v.x) | ((unsigned)f2bf(v.y) << 16);
  o.y = (unsigned)f2bf(v.z) | ((unsigned)f2bf(v.w) << 16);
  d2[li] = o;
}

// ---------- GEMM1 fused with chunk-local scan + aggregate publish ----------
// Round-0 verified form (233.5 us config): bf16 A,B staged via gll16.

__global__ __launch_bounds__(256) void gemm1_fused(
    const unsigned short* __restrict__ A,   // xb bf16 [M x 1024]
    const unsigned short* __restrict__ B,   // Bb bf16 [1024 x 1024]
    unsigned short* __restrict__ u,         // h_local out bf16
    const float* __restrict__ Adiag,
    float* __restrict__ aggbuf) {           // [128][1024] fp32
  __shared__ unsigned short smem[16384];    // sA|sB, reused as sC (32 KB)
  __shared__ float segsum[2][128];
  unsigned short* sA = smem;
  unsigned short* sB = smem + 8192;

  const int tid = threadIdx.x;
  const int wave = tid >> 6, lane = tid & 63;

  const int id = blockIdx.x;
  const int xcd = id & 7, j = id >> 3;
  const int mt = xcd * 16 + (j >> 3);
  const int nt = j & 7;
  const size_t m0 = (size_t)mt * 128;
  const int n0 = nt * 128;

  floatx4 acc[4][4] = {};

  const int srow = wave * 8 + (lane >> 3);
  const int scol = (((lane & 7) ^ ((lane >> 3) & 7)) * 8);  // XOR swizzle
  const unsigned short* gA = A + (m0 + srow) * 1024 + scol;
  const unsigned short* gB = B + ((size_t)n0 + srow) * 1024 + scol;
  unsigned short* lA = sA + wave * 8 * 64;
  unsigned short* lB = sB + wave * 8 * 64;

  const int fr = lane & 15;
  const int frs = fr & 7;
  const int kb = lane >> 4;
  const int wm = (wave & 1) * 64, wn = (wave >> 1) * 64;

  for (int kt = 0; kt < 1024; kt += 64) {
#pragma unroll
    for (int r = 0; r < 4; ++r) {
      gll16(gA + (size_t)r * 32 * 1024 + kt, lA + r * 32 * 64);
      gll16(gB + (size_t)r * 32 * 1024 + kt, lB + r * 32 * 64);
    }
    asm volatile("s_waitcnt vmcnt(0)" ::: "memory");
    __syncthreads();
#pragma unroll
    for (int kk = 0; kk < 64; kk += 32) {
      short8 af[4], bfv[4];
#pragma unroll
      for (int i = 0; i < 4; ++i)
        af[i] = *(const short8*)(sA + (wm + i * 16 + fr) * 64 +
                                 ((((kk >> 3) + kb) ^ frs) * 8));
#pragma unroll
      for (int jj = 0; jj < 4; ++jj)
        bfv[jj] = *(const short8*)(sB + (wn + jj * 16 + fr) * 64 +
                                   ((((kk >> 3) + kb) ^ frs) * 8));
#pragma unroll
      for (int i = 0; i < 4; ++i)
#pragma unroll
        for (int jj = 0; jj < 4; ++jj)
          acc[i][jj] = __builtin_amdgcn_mfma_f32_16x16x32_bf16(
              af[i], bfv[jj], acc[i][jj], 0, 0, 0);
    }
    __syncthreads();
  }

  // stage u tile in LDS (C/D map: col=lane&15, row=(lane>>4)*4+reg)
  const int col = lane & 15;
  const int row4 = (lane >> 4) * 4;
  unsigned short* sC = smem;  // 128x128 bf16
#pragma unroll
  for (int i = 0; i < 4; ++i)
#pragma unroll
    for (int jj = 0; jj < 4; ++jj)
#pragma unroll
      for (int r = 0; r < 4; ++r)
        sC[(wm + i * 16 + row4 + r) * 128 + wn + jj * 16 + col] =
            f2bf(acc[i][jj][r]);
  __syncthreads();

  // chunk-local scan: 2 segments x 64 t per column (tid -> col, seg)
  const int colv = tid & 127;
  const int seg = tid >> 7;
  const float a = Adiag[n0 + colv];
  {
    float s = 0.f;
    const int t0 = seg * 64;
#pragma unroll 8
    for (int t = 0; t < 64; ++t) {
      int idx = (t0 + t) * 128 + colv;
      s = fmaf(a, s, bf2f(sC[idx]));
      sC[idx] = f2bf(s);
    }
    segsum[seg][colv] = s;
  }
  __syncthreads();

  // correct rows 64..127 with seg-0 end state; publish aggregate
  {
    float a2 = a * a, a4 = a2 * a2, a8 = a4 * a4, a16 = a8 * a8;
    float a32 = a16 * a16, a64 = a32 * a32;
    const float s0 = segsum[0][colv];
    const int t0 = 64 + seg * 32;
    float apow = seg ? a32 * a : a;  // a^(t0-64+1)
#pragma unroll 8
    for (int t = 0; t < 32; ++t) {
      int idx = (t0 + t) * 128 + colv;
      sC[idx] = f2bf(fmaf(apow, s0, bf2f(sC[idx])));
      apow *= a;
    }
    if (seg)
      aggbuf[(size_t)mt * 1024 + n0 + colv] =
          fmaf(a64, s0, segsum[1][colv]);
  }
  __syncthreads();

  // coalesced 16B h_local stores
#pragma unroll
  for (int s = 0; s < 8; ++s) {
    int row = wave * 32 + s * 4 + (lane >> 4);
    int c8 = (lane & 15) * 8;
    *(ushort8*)(u + (m0 + row) * (size_t)1024 + n0 + c8) =
        *(const ushort8*)(sC + row * 128 + c8);
  }
}

// ---------- combine: exclusive scan of 16 chunk aggregates per (b, n) ------

__global__ __launch_bounds__(256) void combine_kernel(
    const float* __restrict__ agg, float* __restrict__ carry,
    const float* __restrict__ Adiag) {
  const int id = blockIdx.x * 256 + threadIdx.x;  // 0..8191
  const int b = id >> 10, n = id & (DIM - 1);
  float a = Adiag[n];
  float aL = a;
#pragma unroll
  for (int i = 0; i < 7; ++i) aL *= aL;  // a^128
  float s = 0.f;
#pragma unroll
  for (int c = 0; c < 16; ++c) {
    size_t idx = (size_t)(b * 16 + c) * 1024 + n;
    float local = agg[idx];
    carry[idx] = s;           // carry-in for chunk c
    s = fmaf(aL, s, local);
  }
}

// ---------- apply: h = h_local + a^(t_local+1) * carry  (R0-verified) -----

__global__ __launch_bounds__(256) void apply_kernel(
    unsigned short* __restrict__ u, const float* __restrict__ Adiag,
    const float* __restrict__ carry) {
  const int id = blockIdx.x;          // 0..2047
  const int xcd = id & 7, rem = id >> 3;       // rem 0..255
  const int mt = xcd * 16 + (rem >> 4);        // chunk 0..127 (matches gemm1)
  const int sub = rem & 15;                    // 8-row group within chunk
  const int tg = threadIdx.x >> 7;             // 0..1
  const int ch0 = (threadIdx.x & 127) * 8;

  float a[8], cf[8];
  *(float4*)&a[0] = *(const float4*)(Adiag + ch0);
  *(float4*)&a[4] = *(const float4*)(Adiag + ch0 + 4);
  const float* cp = carry + (size_t)mt * 1024 + ch0;
  *(float4*)&cf[0] = *(const float4*)cp;
  *(float4*)&cf[4] = *(const float4*)(cp + 4);

  const int tl = sub * 8 + tg * 4;  // local t of first row (0..124)
  float apow[8];
#pragma unroll
  for (int j = 0; j < 8; ++j)
    apow[j] = __builtin_amdgcn_exp2f(__builtin_amdgcn_logf(a[j]) *
                                     (float)(tl + 1));
  const size_t base = ((size_t)mt * 128 + tl) * DIM + ch0;
#pragma unroll
  for (int s = 0; s < 4; ++s) {
    ushort8 v = *(const ushort8*)(u + base + (size_t)s * DIM);
    ushort8 o;
#pragma unroll
    for (int j = 0; j < 8; ++j) {
      o[j] = f2bf(fmaf(apow[j], cf[j], bf2f(v[j])));
      apow[j] *= a[j];
    }
    *(ushort8*)(u + base + (size_t)s * DIM) = o;
  }
}

// ---------- GEMM2 pipelined: y = h . W^T + bias ---------------------------
// NEW schedule (T3+T4): BM=256 x BN=128 x BK=64, 512 threads (8 waves, 4x2,
// 64x64 out each), ring of 3 K-tile slots in 144 KB dynamic LDS. While
// computing tile t (slot t%3) we stage tile t+2 (slot (t+2)%3) — write-slot
// never equals read-slot, so no WAR race. ONE barrier per K-tile and
// counted s_waitcnt vmcnt(6) (never 0 mid-loop): each staged load has ~2
// K-tiles of compute to land under. Fragment/swizzle math copied verbatim
// from the verified 128-tile kernel.

__global__ __launch_bounds__(512, 2) void gemm2_pipe(
    const unsigned short* __restrict__ A,   // h bf16 [16384 x 1024]
    const unsigned short* __restrict__ Bw,  // Wb bf16 [1024 x 1024]
    float* __restrict__ C, const float* __restrict__ bias) {
  extern __shared__ unsigned short sm[];
  // A slot s (s=0..2): sm + s*16384          (256 rows x 64 cols bf16)
  // B slot s:          sm + 49152 + s*8192   (128 rows x 64 cols bf16)

  const int tid = threadIdx.x;
  const int wid = tid >> 6, lane = tid & 63;

  // XCD swizzle: 512 blocks, each XCD gets an 8-mt band (A band = 4 MB = L2)
  const int id = blockIdx.x;
  const int xcd = id & 7, j = id >> 3;        // j 0..63
  const int mt = xcd * 8 + (j >> 3);          // 0..63
  const int nt = j & 7;                       // 0..7
  const size_t m0 = (size_t)mt * 256;
  const int n0 = nt * 128;

  floatx4 acc[4][4] = {};

  // staging map: 512 threads, srow 0..63, XOR-swizzled global column
  const int srow = tid >> 3;
  const int scolg = (tid & 7) ^ (srow & 7);
  const unsigned short* gA = A + (m0 + srow) * 1024 + scolg * 8;
  const unsigned short* gB = Bw + ((size_t)n0 + srow) * 1024 + scolg * 8;

  const int fr = lane & 15;
  const int frs = fr & 7;
  const int kb = lane >> 4;
  const int wm = (wid >> 1) * 64;   // 0,64,128,192
  const int wn = (wid & 1) * 64;    // 0,64

#define G2_STAGE(tt, s)                                                     \
  {                                                                         \
    const int kt_ = (tt) * 64;                                              \
    unsigned short* a_ = sm + (s) * 16384 + wid * 512;                      \
    unsigned short* b_ = sm + 49152 + (s) * 8192 + wid * 512;               \
    _Pragma("unroll") for (int r = 0; r < 4; ++r)                           \
        gll16(gA + (size_t)r * 64 * 1024 + kt_, a_ + r * 4096);             \
    _Pragma("unroll") for (int r = 0; r < 2; ++r)                           \
        gll16(gB + (size_t)r * 64 * 1024 + kt_, b_ + r * 4096);             \
  }

  // prologue: tiles 0,1 in flight; wait for tile 0 (6 newest may remain)
  G2_STAGE(0, 0);
  G2_STAGE(1, 1);
  asm volatile("s_waitcnt vmcnt(6)" ::: "memory");
  __syncthreads();

  for (int t = 0; t < 16; ++t) {
    if (t + 2 < 16) G2_STAGE(t + 2, (t + 2) % 3);

    const unsigned short* sA = sm + (t % 3) * 16384;
    const unsigned short* sB = sm + 49152 + (t % 3) * 8192;
    short8 af[4][2], bfv[4][2];
#pragma unroll
    for (int kk = 0; kk < 2; ++kk) {
#pragma unroll
      for (int i = 0; i < 4; ++i)
        af[i][kk] = *(const short8*)(sA + (wm + i * 16 + fr) * 64 +
                                     (((kk * 4 + kb) ^ frs) * 8));
#pragma unroll
      for (int jj = 0; jj < 4; ++jj)
        bfv[jj][kk] = *(const short8*)(sB + (wn + jj * 16 + fr) * 64 +
                                       (((kk * 4 + kb) ^ frs) * 8));
    }
    __builtin_amdgcn_s_setprio(1);
#pragma unroll
    for (int kk = 0; kk < 2; ++kk)
#pragma unroll
      for (int i = 0; i < 4; ++i)
#pragma unroll
        for (int jj = 0; jj < 4; ++jj)
          acc[i][jj] = __builtin_amdgcn_mfma_f32_16x16x32_bf16(
              af[i][kk], bfv[jj][kk], acc[i][jj], 0, 0, 0);
    __builtin_amdgcn_s_setprio(0);

    // tile t+1 must be landed; allow the 6 newest (tile t+2) to remain
    if (t + 2 < 16)
      asm volatile("s_waitcnt vmcnt(6)" ::: "memory");
    else
      asm volatile("s_waitcnt vmcnt(0)" ::: "memory");
    __syncthreads();
  }
#undef G2_STAGE

  const int col = lane & 15;
  const int row4 = (lane >> 4) * 4;
#pragma unroll
  for (int i = 0; i < 4; ++i)
#pragma unroll
    for (int jj = 0; jj < 4; ++jj)
#pragma unroll
      for (int r = 0; r < 4; ++r) {
        size_t m = m0 + wm + i * 16 + row4 + r;
        int n = n0 + wn + jj * 16 + col;
        C[m * 1024 + n] = acc[i][jj][r] + bias[n];
      }
}

// ---------- launcher ----------

extern "C" void kernel_launch(void* const* d_in, const int* in_sizes, int n_in,
                              void* d_out, int out_size, void* d_ws,
                              size_t ws_size, hipStream_t stream) {
  const float* x    = (const float*)d_in[0];
  const float* A    = (const float*)d_in[1];
  const float* B    = (const float*)d_in[2];
  const float* W    = (const float*)d_in[3];
  const float* bias = (const float*)d_in[4];

  char* ws = (char*)d_ws;
  unsigned short* xb   = (unsigned short*)ws;              // 32 MB
  unsigned short* ubuf = (unsigned short*)(ws + 33554432); // 32 MB (h)
  unsigned short* Bb   = (unsigned short*)(ws + 67108864); //  2 MB
  unsigned short* Wb   = (unsigned short*)(ws + 69206016); //  2 MB
  float* aggbuf        = (float*)(ws + 71303168);          // 512 KB
  float* carry         = (float*)(ws + 71827456);          // 512 KB

  static bool attr_set = false;
  if (!attr_set) {
    hipFuncSetAttribute(reinterpret_cast<const void*>(gemm2_pipe),
                        hipFuncAttributeMaxDynamicSharedMemorySize, 147456);
    attr_set = true;
  }

  cast3_kernel<<<(X4 + 2 * M4) / 256, 256, 0, stream>>>(x, B, W, xb, Bb, Wb);

  gemm1_fused<<<1024, 256, 0, stream>>>(xb, Bb, ubuf, A, aggbuf);

  combine_kernel<<<32, 256, 0, stream>>>(aggbuf, carry, A);

  apply_kernel<<<2048, 256, 0, stream>>>(ubuf, A, carry);

  gemm2_pipe<<<512, 512, 147456, stream>>>(ubuf, Wb, (float*)d_out, bias);
}

// Round 5
// 223.699 us; speedup vs baseline: 1.1027x; 1.0262x over previous
//
#include <hip/hip_runtime.h>
#include <stdint.h>

#define BATCH 8
#define SEQ 2048
#define DIM 1024
#define MTOT (BATCH * SEQ)   // 16384

typedef __attribute__((ext_vector_type(8))) short short8;
typedef __attribute__((ext_vector_type(8))) unsigned short ushort8;
typedef __attribute__((ext_vector_type(4))) float floatx4;

// ---------- helpers ----------

__device__ __forceinline__ unsigned short f2bf(float f) {
  union { float f; unsigned u; } c; c.f = f;
  unsigned u = c.u;
  return (unsigned short)((u + 0x7FFFu + ((u >> 16) & 1u)) >> 16);
}
__device__ __forceinline__ float bf2f(unsigned short h) {
  union { unsigned u; float f; } c; c.u = ((unsigned)h) << 16;
  return c.f;
}

__device__ __forceinline__ void gll16(const void* g, void* l) {
  __builtin_amdgcn_global_load_lds(
      (__attribute__((address_space(1))) void*)(uintptr_t)g,
      (__attribute__((address_space(3))) void*)(uintptr_t)l,
      16, 0, 0);
}

// ---------- cast fp32->bf16 (x, B, W), one float4 -> uint2 per thread ------

#define X4 (MTOT * DIM / 4)   // 4194304
#define M4 (DIM * DIM / 4)    // 262144

__global__ __launch_bounds__(256) void cast3_kernel(
    const float* __restrict__ x, const float* __restrict__ B,
    const float* __restrict__ W, unsigned short* __restrict__ xb,
    unsigned short* __restrict__ Bb, unsigned short* __restrict__ Wb) {
  int i = blockIdx.x * 256 + threadIdx.x;
  const float4* s4;
  uint2* d2;
  int li;
  if (i < X4) {
    s4 = (const float4*)x; d2 = (uint2*)xb; li = i;
  } else if (i < X4 + M4) {
    s4 = (const float4*)B; d2 = (uint2*)Bb; li = i - X4;
  } else {
    s4 = (const float4*)W; d2 = (uint2*)Wb; li = i - X4 - M4;
  }
  float4 v = s4[li];
  uint2 o;
  o.x = (unsigned)f2bf(v.x) | ((unsigned)f2bf(v.y) << 16);
  o.y = (unsigned)f2bf(v.z) | ((unsigned)f2bf(v.w) << 16);
  d2[li] = o;
}

// ---------- GEMM1 pipelined + chunk-local scan + aggregate publish --------
// Ring-3 counted-vmcnt schedule (verified in gemm2_pipe, R4): BM=256 x
// BN=128 x BK=64, 512 threads (8 waves 4x2, 64x64 out each), 3 K-tile slots
// in 144 KB dynamic LDS, ONE barrier per K-tile, vmcnt(6) never 0 mid-loop.
// Block covers 2 seq chunks; scan epilogue runs both in parallel
// (512 threads = 2 chunks x 2 segs x 128 cols). MFMA order identical to the
// verified 128-tile kernel -> bitwise-identical u.

__global__ __launch_bounds__(512, 2) void gemm1_pipe(
    const unsigned short* __restrict__ A,   // xb bf16 [16384 x 1024]
    const unsigned short* __restrict__ B,   // Bb bf16 [1024 x 1024]
    unsigned short* __restrict__ u,         // h_local out bf16
    const float* __restrict__ Adiag,
    float* __restrict__ aggbuf) {           // [128][1024] fp32
  extern __shared__ unsigned short sm[];
  // A slot s (s=0..2): sm + s*16384          (256 rows x 64 cols bf16)
  // B slot s:          sm + 49152 + s*8192   (128 rows x 64 cols bf16)
  // epilogue reuse:    sC = sm (256x128 bf16, 64 KB); segsum at +64 KB

  const int tid = threadIdx.x;
  const int wid = tid >> 6, lane = tid & 63;

  const int id = blockIdx.x;                  // 512 blocks
  const int xcd = id & 7, j = id >> 3;        // j 0..63
  const int mt2 = xcd * 8 + (j >> 3);         // 256-row tile 0..63
  const int nt = j & 7;                       // 0..7
  const size_t m0 = (size_t)mt2 * 256;
  const int n0 = nt * 128;

  floatx4 acc[4][4] = {};

  // staging map: 512 threads, srow 0..63, XOR-swizzled global column
  const int srow = tid >> 3;
  const int scolg = (tid & 7) ^ (srow & 7);
  const unsigned short* gA = A + (m0 + srow) * 1024 + scolg * 8;
  const unsigned short* gB = B + ((size_t)n0 + srow) * 1024 + scolg * 8;

  const int fr = lane & 15;
  const int frs = fr & 7;
  const int kb = lane >> 4;
  const int wm = (wid >> 1) * 64;   // 0,64,128,192
  const int wn = (wid & 1) * 64;    // 0,64

#define G1_STAGE(tt, s)                                                     \
  {                                                                         \
    const int kt_ = (tt) * 64;                                              \
    unsigned short* a_ = sm + (s) * 16384 + wid * 512;                      \
    unsigned short* b_ = sm + 49152 + (s) * 8192 + wid * 512;               \
    _Pragma("unroll") for (int r = 0; r < 4; ++r)                           \
        gll16(gA + (size_t)r * 64 * 1024 + kt_, a_ + r * 4096);             \
    _Pragma("unroll") for (int r = 0; r < 2; ++r)                           \
        gll16(gB + (size_t)r * 64 * 1024 + kt_, b_ + r * 4096);             \
  }

  G1_STAGE(0, 0);
  G1_STAGE(1, 1);
  asm volatile("s_waitcnt vmcnt(6)" ::: "memory");
  __syncthreads();

  for (int t = 0; t < 16; ++t) {
    if (t + 2 < 16) G1_STAGE(t + 2, (t + 2) % 3);

    const unsigned short* sA = sm + (t % 3) * 16384;
    const unsigned short* sB = sm + 49152 + (t % 3) * 8192;
    short8 af[4][2], bfv[4][2];
#pragma unroll
    for (int kk = 0; kk < 2; ++kk) {
#pragma unroll
      for (int i = 0; i < 4; ++i)
        af[i][kk] = *(const short8*)(sA + (wm + i * 16 + fr) * 64 +
                                     (((kk * 4 + kb) ^ frs) * 8));
#pragma unroll
      for (int jj = 0; jj < 4; ++jj)
        bfv[jj][kk] = *(const short8*)(sB + (wn + jj * 16 + fr) * 64 +
                                       (((kk * 4 + kb) ^ frs) * 8));
    }
    __builtin_amdgcn_s_setprio(1);
#pragma unroll
    for (int kk = 0; kk < 2; ++kk)
#pragma unroll
      for (int i = 0; i < 4; ++i)
#pragma unroll
        for (int jj = 0; jj < 4; ++jj)
          acc[i][jj] = __builtin_amdgcn_mfma_f32_16x16x32_bf16(
              af[i][kk], bfv[jj][kk], acc[i][jj], 0, 0, 0);
    __builtin_amdgcn_s_setprio(0);

    if (t + 2 < 16)
      asm volatile("s_waitcnt vmcnt(6)" ::: "memory");
    else
      asm volatile("s_waitcnt vmcnt(0)" ::: "memory");
    __syncthreads();
  }
#undef G1_STAGE

  // ---- epilogue: stage 256x128 u tile, dual chunk-local scan ----
  unsigned short* sC = sm;                       // 256x128 bf16 = 64 KB
  float* segsum = (float*)(sm + 32768);          // [2 ch][2 seg][128] fp32

  const int col = lane & 15;
  const int row4 = (lane >> 4) * 4;
#pragma unroll
  for (int i = 0; i < 4; ++i)
#pragma unroll
    for (int jj = 0; jj < 4; ++jj)
#pragma unroll
      for (int r = 0; r < 4; ++r)
        sC[(wm + i * 16 + row4 + r) * 128 + wn + jj * 16 + col] =
            f2bf(acc[i][jj][r]);
  __syncthreads();

  // scan: tid -> (chunk, seg, col); 64 rows per task
  const int ch = tid >> 8;          // 0..1
  const int seg = (tid >> 7) & 1;   // 0..1
  const int colv = tid & 127;
  const float a = Adiag[n0 + colv];
  {
    float s = 0.f;
    const int rbase = ch * 128 + seg * 64;
#pragma unroll 8
    for (int t = 0; t < 64; ++t) {
      int idx = (rbase + t) * 128 + colv;
      s = fmaf(a, s, bf2f(sC[idx]));
      sC[idx] = f2bf(s);
    }
    segsum[(ch * 2 + seg) * 128 + colv] = s;
  }
  __syncthreads();

  // correct rows 64..127 of each chunk with seg-0 end state; publish agg
  {
    float a2 = a * a, a4 = a2 * a2, a8 = a4 * a4, a16 = a8 * a8;
    float a32 = a16 * a16, a64 = a32 * a32;
    const float s0 = segsum[(ch * 2) * 128 + colv];
    const int t0 = 64 + seg * 32;
    float apow = seg ? a32 * a : a;  // a^(t0-64+1)
#pragma unroll 8
    for (int t = 0; t < 32; ++t) {
      int idx = (ch * 128 + t0 + t) * 128 + colv;
      sC[idx] = f2bf(fmaf(apow, s0, bf2f(sC[idx])));
      apow *= a;
    }
    if (seg)
      aggbuf[(size_t)(mt2 * 2 + ch) * 1024 + n0 + colv] =
          fmaf(a64, s0, segsum[(ch * 2 + 1) * 128 + colv]);
  }
  __syncthreads();

  // coalesced 16B h_local stores (256 rows x 128 cols, 8 iters)
#pragma unroll
  for (int s = 0; s < 8; ++s) {
    int row = s * 32 + (tid >> 4);
    int c8 = (tid & 15) * 8;
    *(ushort8*)(u + (m0 + row) * (size_t)1024 + n0 + c8) =
        *(const ushort8*)(sC + row * 128 + c8);
  }
}

// ---------- combine: exclusive scan of 16 chunk aggregates per (b, n) ------

__global__ __launch_bounds__(256) void combine_kernel(
    const float* __restrict__ agg, float* __restrict__ carry,
    const float* __restrict__ Adiag) {
  const int id = blockIdx.x * 256 + threadIdx.x;  // 0..8191
  const int b = id >> 10, n = id & (DIM - 1);
  float a = Adiag[n];
  float aL = a;
#pragma unroll
  for (int i = 0; i < 7; ++i) aL *= aL;  // a^128
  float s = 0.f;
#pragma unroll
  for (int c = 0; c < 16; ++c) {
    size_t idx = (size_t)(b * 16 + c) * 1024 + n;
    float local = agg[idx];
    carry[idx] = s;           // carry-in for chunk c
    s = fmaf(aL, s, local);
  }
}

// ---------- apply: h = h_local + a^(t_local+1) * carry  (R0-verified) -----

__global__ __launch_bounds__(256) void apply_kernel(
    unsigned short* __restrict__ u, const float* __restrict__ Adiag,
    const float* __restrict__ carry) {
  const int id = blockIdx.x;          // 0..2047
  const int xcd = id & 7, rem = id >> 3;       // rem 0..255
  const int mt = xcd * 16 + (rem >> 4);        // chunk 0..127
  const int sub = rem & 15;                    // 8-row group within chunk
  const int tg = threadIdx.x >> 7;             // 0..1
  const int ch0 = (threadIdx.x & 127) * 8;

  float a[8], cf[8];
  *(float4*)&a[0] = *(const float4*)(Adiag + ch0);
  *(float4*)&a[4] = *(const float4*)(Adiag + ch0 + 4);
  const float* cp = carry + (size_t)mt * 1024 + ch0;
  *(float4*)&cf[0] = *(const float4*)cp;
  *(float4*)&cf[4] = *(const float4*)(cp + 4);

  const int tl = sub * 8 + tg * 4;  // local t of first row (0..124)
  float apow[8];
#pragma unroll
  for (int j = 0; j < 8; ++j)
    apow[j] = __builtin_amdgcn_exp2f(__builtin_amdgcn_logf(a[j]) *
                                     (float)(tl + 1));
  const size_t base = ((size_t)mt * 128 + tl) * DIM + ch0;
#pragma unroll
  for (int s = 0; s < 4; ++s) {
    ushort8 v = *(const ushort8*)(u + base + (size_t)s * DIM);
    ushort8 o;
#pragma unroll
    for (int j = 0; j < 8; ++j) {
      o[j] = f2bf(fmaf(apow[j], cf[j], bf2f(v[j])));
      apow[j] *= a[j];
    }
    *(ushort8*)(u + base + (size_t)s * DIM) = o;
  }
}

// ---------- GEMM2 pipelined: y = h . W^T + bias (R4-verified) -------------

__global__ __launch_bounds__(512, 2) void gemm2_pipe(
    const unsigned short* __restrict__ A,   // h bf16 [16384 x 1024]
    const unsigned short* __restrict__ Bw,  // Wb bf16 [1024 x 1024]
    float* __restrict__ C, const float* __restrict__ bias) {
  extern __shared__ unsigned short sm[];

  const int tid = threadIdx.x;
  const int wid = tid >> 6, lane = tid & 63;

  const int id = blockIdx.x;
  const int xcd = id & 7, j = id >> 3;        // j 0..63
  const int mt = xcd * 8 + (j >> 3);          // 0..63
  const int nt = j & 7;                       // 0..7
  const size_t m0 = (size_t)mt * 256;
  const int n0 = nt * 128;

  floatx4 acc[4][4] = {};

  const int srow = tid >> 3;
  const int scolg = (tid & 7) ^ (srow & 7);
  const unsigned short* gA = A + (m0 + srow) * 1024 + scolg * 8;
  const unsigned short* gB = Bw + ((size_t)n0 + srow) * 1024 + scolg * 8;

  const int fr = lane & 15;
  const int frs = fr & 7;
  const int kb = lane >> 4;
  const int wm = (wid >> 1) * 64;   // 0,64,128,192
  const int wn = (wid & 1) * 64;    // 0,64

#define G2_STAGE(tt, s)                                                     \
  {                                                                         \
    const int kt_ = (tt) * 64;                                              \
    unsigned short* a_ = sm + (s) * 16384 + wid * 512;                      \
    unsigned short* b_ = sm + 49152 + (s) * 8192 + wid * 512;               \
    _Pragma("unroll") for (int r = 0; r < 4; ++r)                           \
        gll16(gA + (size_t)r * 64 * 1024 + kt_, a_ + r * 4096);             \
    _Pragma("unroll") for (int r = 0; r < 2; ++r)                           \
        gll16(gB + (size_t)r * 64 * 1024 + kt_, b_ + r * 4096);             \
  }

  G2_STAGE(0, 0);
  G2_STAGE(1, 1);
  asm volatile("s_waitcnt vmcnt(6)" ::: "memory");
  __syncthreads();

  for (int t = 0; t < 16; ++t) {
    if (t + 2 < 16) G2_STAGE(t + 2, (t + 2) % 3);

    const unsigned short* sA = sm + (t % 3) * 16384;
    const unsigned short* sB = sm + 49152 + (t % 3) * 8192;
    short8 af[4][2], bfv[4][2];
#pragma unroll
    for (int kk = 0; kk < 2; ++kk) {
#pragma unroll
      for (int i = 0; i < 4; ++i)
        af[i][kk] = *(const short8*)(sA + (wm + i * 16 + fr) * 64 +
                                     (((kk * 4 + kb) ^ frs) * 8));
#pragma unroll
      for (int jj = 0; jj < 4; ++jj)
        bfv[jj][kk] = *(const short8*)(sB + (wn + jj * 16 + fr) * 64 +
                                       (((kk * 4 + kb) ^ frs) * 8));
    }
    __builtin_amdgcn_s_setprio(1);
#pragma unroll
    for (int kk = 0; kk < 2; ++kk)
#pragma unroll
      for (int i = 0; i < 4; ++i)
#pragma unroll
        for (int jj = 0; jj < 4; ++jj)
          acc[i][jj] = __builtin_amdgcn_mfma_f32_16x16x32_bf16(
              af[i][kk], bfv[jj][kk], acc[i][jj], 0, 0, 0);
    __builtin_amdgcn_s_setprio(0);

    if (t + 2 < 16)
      asm volatile("s_waitcnt vmcnt(6)" ::: "memory");
    else
      asm volatile("s_waitcnt vmcnt(0)" ::: "memory");
    __syncthreads();
  }
#undef G2_STAGE

  const int col = lane & 15;
  const int row4 = (lane >> 4) * 4;
#pragma unroll
  for (int i = 0; i < 4; ++i)
#pragma unroll
    for (int jj = 0; jj < 4; ++jj)
#pragma unroll
      for (int r = 0; r < 4; ++r) {
        size_t m = m0 + wm + i * 16 + row4 + r;
        int n = n0 + wn + jj * 16 + col;
        C[m * 1024 + n] = acc[i][jj][r] + bias[n];
      }
}

// ---------- launcher ----------

extern "C" void kernel_launch(void* const* d_in, const int* in_sizes, int n_in,
                              void* d_out, int out_size, void* d_ws,
                              size_t ws_size, hipStream_t stream) {
  const float* x    = (const float*)d_in[0];
  const float* A    = (const float*)d_in[1];
  const float* B    = (const float*)d_in[2];
  const float* W    = (const float*)d_in[3];
  const float* bias = (const float*)d_in[4];

  char* ws = (char*)d_ws;
  unsigned short* xb   = (unsigned short*)ws;              // 32 MB
  unsigned short* ubuf = (unsigned short*)(ws + 33554432); // 32 MB (h)
  unsigned short* Bb   = (unsigned short*)(ws + 67108864); //  2 MB
  unsigned short* Wb   = (unsigned short*)(ws + 69206016); //  2 MB
  float* aggbuf        = (float*)(ws + 71303168);          // 512 KB
  float* carry         = (float*)(ws + 71827456);          // 512 KB

  static bool attr_set = false;
  if (!attr_set) {
    hipFuncSetAttribute(reinterpret_cast<const void*>(gemm1_pipe),
                        hipFuncAttributeMaxDynamicSharedMemorySize, 147456);
    hipFuncSetAttribute(reinterpret_cast<const void*>(gemm2_pipe),
                        hipFuncAttributeMaxDynamicSharedMemorySize, 147456);
    attr_set = true;
  }

  cast3_kernel<<<(X4 + 2 * M4) / 256, 256, 0, stream>>>(x, B, W, xb, Bb, Wb);

  gemm1_pipe<<<512, 512, 147456, stream>>>(xb, Bb, ubuf, A, aggbuf);

  combine_kernel<<<32, 256, 0, stream>>>(aggbuf, carry, A);

  apply_kernel<<<2048, 256, 0, stream>>>(ubuf, A, carry);

  gemm2_pipe<<<512, 512, 147456, stream>>>(ubuf, Wb, (float*)d_out, bias);
}